// Round 15
// baseline (143.892 us; speedup 1.0000x reference)
//
#include <hip/hip_runtime.h>
#include <stdint.h>

// jax_threefry_partitionable=True: 32-bit random bits are (out0 ^ out1) of
// threefry2x32(key, (hi32(i)=0, lo32(i)=i)), key = (0, 42).
// Ordering note: JAX's normal = erfinv(uniform(mantissa)) is strictly
// monotone in the 23 mantissa bits, so top-k order == mantissa order with
// lower-index tie-break. Verified passing rounds 2/4/6/10/11/12/14 (absmax
// 0.0112 vs threshold 0.0844 = fp32 sum-order noise).
// CONFIG = r14 best-measured (143.8 us): topk-unrolled + hist96 + gemm768.
// Delta this round: topk processes 2 samples per wave (two independent
// threshold-search chains interleave; wave count 48000 -> 24000).
constexpr int BF   = 96;    // B * MAX_FRAMES
constexpr int NS   = 500;   // NUM_SAMPLES
constexpr int DSP  = 196;   // N - 1 spatial tokens
constexpr int KSEL = 49;    // TOPK
constexpr int NTOK = 197;   // N
constexpr int DIM  = 512;   // D
constexpr int ROWSTRIDE = 64;   // padded byte stride of one sample's idx row

__device__ __forceinline__ uint32_t rotl32(uint32_t x, int r) {
  // single v_alignbit_b32: rotl(x,r) = rotr(x,32-r)
  return __builtin_amdgcn_alignbit(x, x, 32 - r);
}

__device__ __forceinline__ void threefry2x32(uint32_t x0, uint32_t x1,
                                             uint32_t& o0, uint32_t& o1) {
  const uint32_t ks0 = 0u, ks1 = 42u, ks2 = 0u ^ 42u ^ 0x1BD11BDAu;
  x0 += ks0; x1 += ks1;
#define TF_R(r) { x0 += x1; x1 = rotl32(x1, (r)); x1 ^= x0; }
  TF_R(13) TF_R(15) TF_R(26) TF_R(6)   x0 += ks1; x1 += ks2 + 1u;
  TF_R(17) TF_R(29) TF_R(16) TF_R(24)  x0 += ks2; x1 += ks0 + 2u;
  TF_R(13) TF_R(15) TF_R(26) TF_R(6)   x0 += ks0; x1 += ks1 + 3u;
  TF_R(17) TF_R(29) TF_R(16) TF_R(24)  x0 += ks1; x1 += ks2 + 4u;
  TF_R(13) TF_R(15) TF_R(26) TF_R(6)   x0 += ks2; x1 += ks0 + 5u;
#undef TF_R
  o0 = x0; o1 = x1;
}

__device__ __forceinline__ uint32_t noise_bits(uint32_t p) {
  uint32_t o0, o1;
  threefry2x32(0u, p, o0, o1);
  return o0 ^ o1;
}

// TWO samples per wave: 8 threefry evals/lane (independent -> deep VALU
// pipelining); two independent 23-bit threshold searches interleaved in one
// unrolled loop (row-A VALU overlaps row-B SALU chain). Ties -> lowest index.
// Writes the 49 SORTED selected indices of each sample as bytes.
__global__ __launch_bounds__(256)
void topk_idx_kernel(uint8_t* __restrict__ idxbuf) {
  const int lane = threadIdx.x & 63;
  const int wid  = (blockIdx.x << 2) | (threadIdx.x >> 6);   // 0..23999
  const uint32_t s0 = (uint32_t)wid * 2u;                    // sample pair
  const uint32_t base0 = s0 * (uint32_t)DSP;
  const uint32_t base1 = base0 + (uint32_t)DSP;

  uint32_t m[8];                 // [0..3] row0, [4..7] row1
#pragma unroll
  for (int g = 0; g < 4; ++g) {
    const int j = (g << 6) | lane;
    uint32_t v0 = 0u, v1 = 0u;
    if (j < DSP) {
      v0 = noise_bits(base0 + (uint32_t)j) >> 9;   // 23-bit mantissa
      v1 = noise_bits(base1 + (uint32_t)j) >> 9;
    }
    m[g] = v0;
    m[4 + g] = v1;
  }

  // Two independent searches: largest T with count(m >= T) >= 49.
  // cand >= 1 so padding lanes (m=0) never count.
  uint32_t T0 = 0u, T1 = 0u;
#pragma unroll
  for (int bit = 22; bit >= 0; --bit) {
    const uint32_t cand0 = T0 | (1u << bit);
    const uint32_t cand1 = T1 | (1u << bit);
    const int c0 = __popcll(__ballot(m[0] >= cand0))
                 + __popcll(__ballot(m[1] >= cand0))
                 + __popcll(__ballot(m[2] >= cand0))
                 + __popcll(__ballot(m[3] >= cand0));
    const int c1 = __popcll(__ballot(m[4] >= cand1))
                 + __popcll(__ballot(m[5] >= cand1))
                 + __popcll(__ballot(m[6] >= cand1))
                 + __popcll(__ballot(m[7] >= cand1));
    if (c0 >= KSEL) T0 = cand0;
    if (c1 >= KSEL) T1 = cand1;
  }

  const uint64_t below = (1ull << lane) - 1ull;
#pragma unroll
  for (int r = 0; r < 2; ++r) {
    const uint32_t T = r ? T1 : T0;
    const uint32_t* mr = &m[4 * r];

    uint64_t gt[4], eq[4];
#pragma unroll
    for (int g = 0; g < 4; ++g) {
      gt[g] = __ballot(mr[g] > T);
      eq[g] = __ballot(mr[g] == T);
    }
    eq[3] &= 0xFull;  // strip padding lanes (j >= 196)

    const int ngt = __popcll(gt[0]) + __popcll(gt[1])
                  + __popcll(gt[2]) + __popcll(gt[3]);
    const int need = KSEL - ngt;     // 1..eq_total
    const int e0 = __popcll(eq[0]), e1 = __popcll(eq[1]), e2 = __popcll(eq[2]);

    // take the lowest-index `need` members of the eq set
    uint64_t fin[4];
    fin[0] = gt[0] | __ballot(((eq[0] >> lane) & 1ull) &&
                              (__popcll(eq[0] & below) < need));
    fin[1] = gt[1] | __ballot(((eq[1] >> lane) & 1ull) &&
                              (e0 + __popcll(eq[1] & below) < need));
    fin[2] = gt[2] | __ballot(((eq[2] >> lane) & 1ull) &&
                              (e0 + e1 + __popcll(eq[2] & below) < need));
    fin[3] = gt[3] | __ballot(((eq[3] >> lane) & 1ull) &&
                              (e0 + e1 + e2 + __popcll(eq[3] & below) < need));

    const int c0 = __popcll(fin[0]);
    const int c1 = c0 + __popcll(fin[1]);
    const int c2 = c1 + __popcll(fin[2]);

    uint8_t* row = idxbuf + (size_t)(s0 + r) * ROWSTRIDE;
    if ((fin[0] >> lane) & 1ull) row[__popcll(fin[0] & below)]      = (uint8_t)lane;
    if ((fin[1] >> lane) & 1ull) row[c0 + __popcll(fin[1] & below)] = (uint8_t)(64 + lane);
    if ((fin[2] >> lane) & 1ull) row[c1 + __popcll(fin[2] & below)] = (uint8_t)(128 + lane);
    if ((fin[3] >> lane) & 1ull) row[c2 + __popcll(fin[3] & below)] = (uint8_t)(192 + lane);
  }
}

// B1: one block per b. Coalesced uint4 loads of the 49-byte rank rows ->
// LDS histogram cnt[k][j] -> u16 to ws. Also copies the cls row.
__global__ __launch_bounds__(512)
void hist_kernel(const float* __restrict__ x,
                 const uint8_t* __restrict__ idxbuf,
                 uint16_t* __restrict__ cnt,
                 float* __restrict__ out) {
  const int b = blockIdx.x;
  const int t = threadIdx.x;

  __shared__ uint32_t hist[KSEL * DSP];   // 38.4 KB
  for (int i = t; i < KSEL * DSP; i += 512) hist[i] = 0u;
  __syncthreads();

  const uint32_t* rows = (const uint32_t*)(idxbuf + (size_t)b * NS * ROWSTRIDE);
  for (int c = t; c < NS * 4; c += 512) {   // 2000 16B chunks, coalesced
    const int s = c >> 2, part = c & 3;
    const uint4 v = *(const uint4*)(rows + s * 16 + part * 4);
    if (part < 3) {
      const int kbase = part * 16;
#pragma unroll
      for (int q = 0; q < 4; ++q) {
        uint32_t w = (&v.x)[q];
#pragma unroll
        for (int bb = 0; bb < 4; ++bb) {
          atomicAdd(&hist[(kbase + q * 4 + bb) * DSP + (w & 0xffu)], 1u);
          w >>= 8;
        }
      }
    } else {
      atomicAdd(&hist[48 * DSP + (v.x & 0xffu)], 1u);   // k = 48
    }
  }
  __syncthreads();

  uint16_t* cb = cnt + (size_t)b * KSEL * DSP;
  for (int i = t; i < KSEL * DSP; i += 512) cb[i] = (uint16_t)hist[i];

  // cls row
  out[(size_t)b * (1 + KSEL) * DIM + t] = x[(size_t)b * NTOK * DIM + t];
}

// B2: out[b,1+k,:] = (cnt[b] @ x[b,1:,:]) / NS, dense tiled.
// Block = (b, 64-col tile); 256 threads = 16 dt x 16 kg; thread tile 4k x 4d.
// bid = dtile*96 + b -> all 8 tiles of one b land on the same XCD (96%8==0).
// cnt staged in LDS as u16 PAIRS (25 KB -> 6 blocks/CU); j processed
// two-at-a-time, unroll 2 -> 4 global float4 loads in flight.
__global__ __launch_bounds__(256)
void gemm_kernel(const float* __restrict__ x,
                 const uint16_t* __restrict__ cnt,
                 float* __restrict__ out) {
  const int b = blockIdx.x % BF;
  const int dtile = blockIdx.x / BF;        // 0..7
  const int t = threadIdx.x;
  const int dt = t & 15, kg = t >> 4;

  constexpr int JP = DSP / 2;               // 98 u16-pairs per row
  __shared__ uint32_t cfp[64 * JP];         // 25088 B, rows 49..63 zero
  const uint32_t* cp = (const uint32_t*)(cnt + (size_t)b * KSEL * DSP);
  for (int i = t; i < KSEL * JP; i += 256) cfp[i] = cp[i];
  for (int i = KSEL * JP + t; i < 64 * JP; i += 256) cfp[i] = 0u;
  __syncthreads();

  const float* xb = x + (size_t)b * NTOK * DIM + DIM /*skip cls*/
                  + dtile * 64 + dt * 4;
  float4 acc[4] = {};
#pragma unroll 2
  for (int j2 = 0; j2 < JP; ++j2) {
    const float4 xv0 = *(const float4*)(xb + (size_t)(2 * j2) * DIM);
    const float4 xv1 = *(const float4*)(xb + (size_t)(2 * j2 + 1) * DIM);
#pragma unroll
    for (int i = 0; i < 4; ++i) {
      const uint32_t pr = cfp[(kg + 16 * i) * JP + j2];   // 16-lane broadcast
      const float c0 = (float)(pr & 0xffffu);
      const float c1 = (float)(pr >> 16);
      acc[i].x = fmaf(c0, xv0.x, acc[i].x);
      acc[i].y = fmaf(c0, xv0.y, acc[i].y);
      acc[i].z = fmaf(c0, xv0.z, acc[i].z);
      acc[i].w = fmaf(c0, xv0.w, acc[i].w);
      acc[i].x = fmaf(c1, xv1.x, acc[i].x);
      acc[i].y = fmaf(c1, xv1.y, acc[i].y);
      acc[i].z = fmaf(c1, xv1.z, acc[i].z);
      acc[i].w = fmaf(c1, xv1.w, acc[i].w);
    }
  }

  float* ob = out + (size_t)b * (1 + KSEL) * DIM + dtile * 64 + dt * 4;
  const float inv = 1.0f / (float)NS;
#pragma unroll
  for (int i = 0; i < 4; ++i) {
    const int k = kg + 16 * i;
    if (k < KSEL) {
      float4 r;
      r.x = acc[i].x * inv; r.y = acc[i].y * inv;
      r.z = acc[i].z * inv; r.w = acc[i].w * inv;
      *(float4*)(ob + (size_t)(1 + k) * DIM) = r;
    }
  }
}

extern "C" void kernel_launch(void* const* d_in, const int* in_sizes, int n_in,
                              void* d_out, int out_size, void* d_ws, size_t ws_size,
                              hipStream_t stream) {
  const float* x = (const float*)d_in[0];
  float* out = (float*)d_out;
  uint8_t* idxbuf = (uint8_t*)d_ws;                        // 3,072,000 B
  uint16_t* cnt = (uint16_t*)((uint8_t*)d_ws +
                              (size_t)BF * NS * ROWSTRIDE); // 1,843,968 B

  topk_idx_kernel<<<dim3(BF * NS / 8), 256, 0, stream>>>(idxbuf);
  hist_kernel<<<dim3(BF), 512, 0, stream>>>(x, idxbuf, cnt, out);
  gemm_kernel<<<dim3(BF * 8), 256, 0, stream>>>(x, cnt, out);
}